// Round 9
// baseline (41.629 us; speedup 1.0000x reference)
//
#include <hip/hip_runtime.h>

// APLoss (r2d2 QAPLoss). B=2, H=W=32 -> N=M=1024/batch, D=128, 25 bins.
// u = 24*(1-sim); cumsum_k of triangular bins = clamp(k+1-u, 0, 1).
// K1 grid-sample -> K2 fused sim+hist (block = 16q x 512m; qpb=16 halves
// cross-XCD dbt traffic vs qpb=8) -> K3 single-block half-combine + AP + mean.

#define NQB 25

// DPP butterfly add over 16-lane rows (pure VALU, no LDS pipe).
template<int CTRL>
__device__ __forceinline__ float dppadd(float v) {
    int s = __builtin_amdgcn_update_dpp(0, __float_as_int(v), CTRL, 0xf, 0xf, true);
    return v + __int_as_float(s);
}
__device__ __forceinline__ float red16(float v) {
    v = dppadd<0xB1>(v);   // quad_perm xor1
    v = dppadd<0x4E>(v);   // quad_perm xor2
    v = dppadd<0x141>(v);  // row_half_mirror = xor7
    v = dppadd<0x140>(v);  // row_mirror      = xor15
    return v;              // every lane: its 16-lane-row sum
}

// ---- K1: bilinear grid-sample desc2 -> dbt[b][c][m]; block = (b,c) ---------
__global__ __launch_bounds__(256) void k_gs(const float* __restrict__ desc2,
                                            const float* __restrict__ grd,
                                            float* __restrict__ dbt)
{
    __shared__ float plane[1024];
    int r = blockIdx.x;            // b*128 + c
    int b = r >> 7;
    int tid = threadIdx.x;
    const float* src = desc2 + ((size_t)r << 10);
    *(float4*)&plane[tid * 4] = *(const float4*)&src[tid * 4];
    __syncthreads();
#pragma unroll
    for (int e = 0; e < 4; e++) {
        int m = tid + (e << 8);
        int pos = (b << 10) + m;
        float2 g = ((const float2*)grd)[pos];
        float fx = ((g.x + 1.f) * 32.f - 1.f) * 0.5f;
        float fy = ((g.y + 1.f) * 32.f - 1.f) * 0.5f;
        float x0f = floorf(fx), y0f = floorf(fy);
        float wx1 = fx - x0f, wy1 = fy - y0f;
        float wx0 = 1.f - wx1, wy0 = 1.f - wy1;
        int x0 = (int)x0f, y0 = (int)y0f;
        float acc = 0.f;
        if ((unsigned)y0 < 32u && (unsigned)x0 < 32u)
            acc += wy0 * wx0 * plane[(y0 << 5) + x0];
        if ((unsigned)y0 < 32u && (unsigned)(x0 + 1) < 32u)
            acc += wy0 * wx1 * plane[(y0 << 5) + x0 + 1];
        if ((unsigned)(y0 + 1) < 32u && (unsigned)x0 < 32u)
            acc += wy1 * wx0 * plane[((y0 + 1) << 5) + x0];
        if ((unsigned)(y0 + 1) < 32u && (unsigned)(x0 + 1) < 32u)
            acc += wy1 * wx1 * plane[((y0 + 1) << 5) + x0 + 1];
        dbt[((size_t)r << 10) + m] = acc;
    }
}

// ---- K2: fused sim + histogram; block = 16 q x 512 m, 512 thr (8 waves) ----
// Sim: thread owns one m, acc[16] over queries; q-side wave-uniform scalar
// loads (16 consecutive floats per c). Hist: wave w -> queries 2w,2w+1,
// lane l owns m = l + 64e (e<8); labels prefetched pre-sim.
// Output partials[qgrp*1600 + h*800 + j*16 + q], j<25: CN_j, j>=25: CR_{j-25}.
__global__ __launch_bounds__(512) void k_main(const float* __restrict__ desc1,
                                              const float* __restrict__ dbt,
                                              const int* __restrict__ label,
                                              float* __restrict__ partials)
{
    __shared__ float s[16][512];        // sim tile (32 KB)
    __shared__ float CNs[16][4][NQB];
    __shared__ float CRs[16][4][NQB];

    int tid = threadIdx.x;
    int bid = blockIdx.x;
    int qgrp = bid >> 1;               // 16-query group
    int h = bid & 1;                   // m half
    int qg0 = qgrp << 4;               // global query base (b*1024 + n0)
    int b = qg0 >> 10;
    int n0 = qg0 & 1023;
    int m0 = h << 9;

    // ---- label prefetch (registers; latency hides under sim) ----
    int w = tid >> 6, l = tid & 63;
    float lf[2][8];
#pragma unroll
    for (int q2 = 0; q2 < 2; q2++) {
        const int* lp = label + ((size_t)(qg0 + (w << 1) + q2) << 10) + m0 + l;
#pragma unroll
        for (int e = 0; e < 8; e++) lf[q2][e] = (float)lp[(size_t)(e << 6)];
    }

    // ---- sim: thread owns m = m0 + tid, all 16 q ----
    const float* dp = dbt + ((size_t)b << 17) + m0 + tid;
    const float* d1 = desc1 + ((size_t)b << 17) + n0;  // q-row: d1[(c<<10)+qq]

    float acc[16];
#pragma unroll
    for (int qq = 0; qq < 16; qq++) acc[qq] = 0.f;

#pragma unroll 4
    for (int c = 0; c < 128; c++) {
        float dv = dp[(size_t)c << 10];
#pragma unroll
        for (int qq = 0; qq < 16; qq++)
            acc[qq] = fmaf(d1[((size_t)c << 10) + qq], dv, acc[qq]);
    }
#pragma unroll
    for (int qq = 0; qq < 16; qq++) s[qq][tid] = acc[qq];
    __syncthreads();

    // ---- hist: wave w -> queries 2w, 2w+1; lane l -> m = l + 64e ----
#pragma unroll
    for (int q2 = 0; q2 < 2; q2++) {
        int q = (w << 1) + q2;
        float CN[NQB], CR[NQB];
#pragma unroll
        for (int k = 0; k < NQB; k++) { CN[k] = 0.f; CR[k] = 0.f; }
#pragma unroll
        for (int e = 0; e < 8; e++) {
            float sv = s[q][l + (e << 6)];
            float u = fmaf(-24.f, sv, 24.f);
            float lfv = lf[q2][e];
#pragma unroll
            for (int k = 0; k < NQB; k++) {
                float t = fminf(fmaxf((float)(k + 1) - u, 0.f), 1.f);  // v_med3
                CN[k] += t;
                CR[k] = fmaf(lfv, t, CR[k]);
            }
        }
#pragma unroll
        for (int k = 0; k < NQB; k++) { CN[k] = red16(CN[k]); CR[k] = red16(CR[k]); }
        if ((l & 15) == 0) {
            int rec = l >> 4;
#pragma unroll
            for (int k = 0; k < NQB; k++) { CNs[q][rec][k] = CN[k]; CRs[q][rec][k] = CR[k]; }
        }
    }
    __syncthreads();

    // ---- combine 4 records -> global partials (this half) ----
    float* P = partials + (size_t)qgrp * 1600 + h * 800;
    for (int idx = tid; idx < 800; idx += 512) {
        int q = idx & 15, j = idx >> 4;
        int k = (j < 25) ? j : (j - 25);
        float v = (j < 25)
            ? (CNs[q][0][k] + CNs[q][1][k] + CNs[q][2][k] + CNs[q][3][k])
            : (CRs[q][0][k] + CRs[q][1][k] + CRs[q][2][k] + CRs[q][3][k]);
        P[idx] = v;
    }
}

// ---- K3: combine m-halves + AP per query + global mean -> d_out ------------
__global__ __launch_bounds__(1024) void k_tail(const float* __restrict__ partials,
                                               float* __restrict__ out,
                                               int npos, float invn)
{
    int tid = threadIdx.x;
    float apsum = 0.f;
    for (int qg = tid; qg < npos; qg += 1024) {
        const float* Pg = partials + (size_t)(qg >> 4) * 1600;
        int q = qg & 15;
        float ap = 0.f, prev = 0.f;
#pragma unroll
        for (int k = 0; k < NQB; k++) {
            float cn = Pg[(k << 4) + q] + Pg[800 + (k << 4) + q];
            float cr = Pg[((25 + k) << 4) + q] + Pg[800 + ((25 + k) << 4) + q];
            float pr = cr / (1e-16f + cn);
            ap += pr * (cr - prev);
            prev = cr;
        }
        apsum += ap / prev;
    }
    for (int off = 32; off; off >>= 1) apsum += __shfl_xor(apsum, off, 64);
    __shared__ float wsum[16];
    if ((tid & 63) == 0) wsum[tid >> 6] = apsum;
    __syncthreads();
    if (tid == 0) {
        float v = 0.f;
#pragma unroll
        for (int i = 0; i < 16; i++) v += wsum[i];
        out[0] = v * invn;
    }
}

extern "C" void kernel_launch(void* const* d_in, const int* in_sizes, int n_in,
                              void* d_out, int out_size, void* d_ws, size_t ws_size,
                              hipStream_t stream)
{
    const float* desc1 = (const float*)d_in[0];
    const float* desc2 = (const float*)d_in[1];
    // d_in[2] = reliability: unused by the reference output
    const float* grd   = (const float*)d_in[3];
    const int*   label = (const int*)d_in[4];

    int B = in_sizes[0] / (128 * 1024);
    int npos = B * 1024;
    int ngrp = npos / 16;

    float* ws = (float*)d_ws;
    float* dbt      = ws;                          // npos*128 floats ([b][c][m])
    float* partials = dbt + (size_t)npos * 128;    // ngrp*1600 floats
    float* out = (float*)d_out;

    k_gs<<<B * 128, 256, 0, stream>>>(desc2, grd, dbt);
    k_main<<<ngrp * 2, 512, 0, stream>>>(desc1, dbt, label, partials);
    k_tail<<<1, 1024, 0, stream>>>(partials, out, npos, 1.f / (float)npos);
}

// Round 10
// 27.893 us; speedup vs baseline: 1.4925x; 1.4925x over previous
//
#include <hip/hip_runtime.h>

// APLoss (r2d2 QAPLoss). B=2, H=W=32 -> N=M=1024/batch, D=128, 25 bins.
// u = 24*(1-sim); cumsum_k of triangular bins = clamp(k+1-u, 0, 1).
// R5 structure (best measured): k_gs -> k_main (block = 8q x ALL 1024m,
// 512 thr, scalar q-loads) -> k_final.  R10 adds: 2-deep ping-pong register
// pipeline on the dbt loads + pre-sim label prefetch (both latency-hiding).

#define NQB 25

// DPP butterfly add over 16-lane rows (pure VALU, no LDS pipe).
template<int CTRL>
__device__ __forceinline__ float dppadd(float v) {
    int s = __builtin_amdgcn_update_dpp(0, __float_as_int(v), CTRL, 0xf, 0xf, true);
    return v + __int_as_float(s);
}
__device__ __forceinline__ float red16(float v) {
    v = dppadd<0xB1>(v);   // quad_perm xor1
    v = dppadd<0x4E>(v);   // quad_perm xor2
    v = dppadd<0x141>(v);  // row_half_mirror = xor7
    v = dppadd<0x140>(v);  // row_mirror      = xor15
    return v;              // every lane: its 16-lane-row sum
}

// ---- K1: bilinear grid-sample desc2 -> dbt[b][c][m]; block = (b,c) ---------
__global__ __launch_bounds__(256) void k_gs(const float* __restrict__ desc2,
                                            const float* __restrict__ grd,
                                            float* __restrict__ dbt)
{
    __shared__ float plane[1024];
    int r = blockIdx.x;            // b*128 + c
    int b = r >> 7;
    int tid = threadIdx.x;
    const float* src = desc2 + ((size_t)r << 10);
    *(float4*)&plane[tid * 4] = *(const float4*)&src[tid * 4];
    __syncthreads();
#pragma unroll
    for (int e = 0; e < 4; e++) {
        int m = tid + (e << 8);
        int pos = (b << 10) + m;
        float2 g = ((const float2*)grd)[pos];
        float fx = ((g.x + 1.f) * 32.f - 1.f) * 0.5f;
        float fy = ((g.y + 1.f) * 32.f - 1.f) * 0.5f;
        float x0f = floorf(fx), y0f = floorf(fy);
        float wx1 = fx - x0f, wy1 = fy - y0f;
        float wx0 = 1.f - wx1, wy0 = 1.f - wy1;
        int x0 = (int)x0f, y0 = (int)y0f;
        float acc = 0.f;
        if ((unsigned)y0 < 32u && (unsigned)x0 < 32u)
            acc += wy0 * wx0 * plane[(y0 << 5) + x0];
        if ((unsigned)y0 < 32u && (unsigned)(x0 + 1) < 32u)
            acc += wy0 * wx1 * plane[(y0 << 5) + x0 + 1];
        if ((unsigned)(y0 + 1) < 32u && (unsigned)x0 < 32u)
            acc += wy1 * wx0 * plane[((y0 + 1) << 5) + x0];
        if ((unsigned)(y0 + 1) < 32u && (unsigned)(x0 + 1) < 32u)
            acc += wy1 * wx1 * plane[((y0 + 1) << 5) + x0 + 1];
        dbt[((size_t)r << 10) + m] = acc;
    }
}

// ---- sim helpers: chunk = 8 consecutive c ----------------------------------
__device__ __forceinline__ void loadc(const float* __restrict__ dp, int ch,
                                      float* d)
{
    int cb = ch << 3;
#pragma unroll
    for (int i = 0; i < 8; i++) {
        d[i]     = dp[(size_t)(cb + i) << 10];          // m = tid
        d[8 + i] = dp[(((size_t)(cb + i)) << 10) + 512]; // m = tid + 512
    }
}
__device__ __forceinline__ void fmac(const float* __restrict__ d1, int ch,
                                     const float* d, float* a0, float* a1)
{
    int cb = ch << 3;
#pragma unroll
    for (int i = 0; i < 8; i++) {
        const float* qp = d1 + ((size_t)(cb + i) << 10);
#pragma unroll
        for (int qq = 0; qq < 8; qq++) {
            float qv = qp[qq];   // wave-uniform -> scalar load
            a0[qq] = fmaf(qv, d[i], a0[qq]);
            a1[qq] = fmaf(qv, d[8 + i], a1[qq]);
        }
    }
}

// ---- K2: fused sim + histogram + AP; block = 8 q x ALL 1024 m, 512 thr -----
__global__ __launch_bounds__(512) void k_main(const float* __restrict__ desc1,
                                              const float* __restrict__ dbt,
                                              const int* __restrict__ label,
                                              float* __restrict__ appart)
{
    __shared__ float s[8][1024];    // sim tile
    __shared__ float CNs[8][4][NQB];
    __shared__ float CRs[8][4][NQB];
    __shared__ float apb[8];

    int tid = threadIdx.x;
    int qg0 = blockIdx.x << 3;      // global query base (b*1024 + n0)
    int b = qg0 >> 10;
    int n0 = qg0 & 1023;

    // ---- label prefetch (registers, static indices; hides under sim) ----
    int q = tid >> 6, l = tid & 63; // hist roles
    const int* lp = label + ((size_t)(qg0 + q) << 10) + l;
    int lv[16];
#pragma unroll
    for (int e = 0; e < 16; e++) lv[e] = lp[(size_t)(e << 6)];

    // ---- sim phase: 2-deep ping-pong pipeline over 16 chunks of 8 c ----
    const float* d1 = desc1 + ((size_t)b << 17) + n0;  // q-row: d1[(c<<10)+qq]
    const float* dp = dbt + ((size_t)b << 17) + tid;

    float a0[8], a1[8];
#pragma unroll
    for (int qq = 0; qq < 8; qq++) { a0[qq] = 0.f; a1[qq] = 0.f; }

    float dA[16], dB[16];
    loadc(dp, 0, dA);
    for (int ch = 0; ch < 16; ch += 2) {
        loadc(dp, ch + 1, dB);          // issue next chunk
        fmac(d1, ch, dA, a0, a1);       // consume current
        if (ch + 2 < 16) loadc(dp, ch + 2, dA);
        fmac(d1, ch + 1, dB, a0, a1);
    }
#pragma unroll
    for (int qq = 0; qq < 8; qq++) { s[qq][tid] = a0[qq]; s[qq][tid + 512] = a1[qq]; }
    __syncthreads();

    // ---- histogram: wave = query, lane l owns m = l + 64e (conflict-free) --
    float CN[NQB], CR[NQB];
#pragma unroll
    for (int k = 0; k < NQB; k++) { CN[k] = 0.f; CR[k] = 0.f; }
#pragma unroll
    for (int e = 0; e < 16; e++) {
        float sv = s[q][l + (e << 6)];
        float lfv = (float)lv[e];
        float u = fmaf(-24.f, sv, 24.f);
#pragma unroll
        for (int k = 0; k < NQB; k++) {
            float t = fminf(fmaxf((float)(k + 1) - u, 0.f), 1.f);  // v_med3
            CN[k] += t;
            CR[k] = fmaf(lfv, t, CR[k]);
        }
    }
#pragma unroll
    for (int k = 0; k < NQB; k++) { CN[k] = red16(CN[k]); CR[k] = red16(CR[k]); }
    if ((l & 15) == 0) {
        int rec = l >> 4;
#pragma unroll
        for (int k = 0; k < NQB; k++) { CNs[q][rec][k] = CN[k]; CRs[q][rec][k] = CR[k]; }
    }
    __syncthreads();

    // ---- AP per query (8 threads), block sum -> 1 float ----
    if (tid < 8) {
        float ap = 0.f, prev = 0.f;
#pragma unroll
        for (int k = 0; k < NQB; k++) {
            float cn = CNs[tid][0][k] + CNs[tid][1][k] + CNs[tid][2][k] + CNs[tid][3][k];
            float cr = CRs[tid][0][k] + CRs[tid][1][k] + CRs[tid][2][k] + CRs[tid][3][k];
            float pr = cr / (1e-16f + cn);
            ap += pr * (cr - prev);
            prev = cr;
        }
        apb[tid] = ap / prev;
    }
    __syncthreads();
    if (tid == 0) {
        float v = 0.f;
#pragma unroll
        for (int q2 = 0; q2 < 8; q2++) v += apb[q2];
        appart[blockIdx.x] = v;
    }
}

// ---- K3: final reduce of per-block sums -> d_out ---------------------------
__global__ __launch_bounds__(256) void k_final(const float* __restrict__ appart,
                                               float* __restrict__ out,
                                               int nb, float invn)
{
    int tid = threadIdx.x;
    float v = 0.f;
    for (int i = tid; i < nb; i += 256) v += appart[i];
    for (int off = 32; off; off >>= 1) v += __shfl_xor(v, off, 64);
    __shared__ float wsum[4];
    if ((tid & 63) == 0) wsum[tid >> 6] = v;
    __syncthreads();
    if (tid == 0) out[0] = (wsum[0] + wsum[1] + wsum[2] + wsum[3]) * invn;
}

extern "C" void kernel_launch(void* const* d_in, const int* in_sizes, int n_in,
                              void* d_out, int out_size, void* d_ws, size_t ws_size,
                              hipStream_t stream)
{
    const float* desc1 = (const float*)d_in[0];
    const float* desc2 = (const float*)d_in[1];
    // d_in[2] = reliability: unused by the reference output
    const float* grd   = (const float*)d_in[3];
    const int*   label = (const int*)d_in[4];

    int B = in_sizes[0] / (128 * 1024);
    int npos = B * 1024;

    float* ws = (float*)d_ws;
    float* dbt    = ws;                          // npos*128 floats ([b][c][m])
    float* appart = dbt + (size_t)npos * 128;    // npos/8 floats
    float* out = (float*)d_out;

    k_gs<<<B * 128, 256, 0, stream>>>(desc2, grd, dbt);
    k_main<<<npos / 8, 512, 0, stream>>>(desc1, dbt, label, appart);
    k_final<<<1, 256, 0, stream>>>(appart, out, npos / 8, 1.f / (float)npos);
}